// Round 1
// baseline (2361.227 us; speedup 1.0000x reference)
//
#include <hip/hip_runtime.h>
#include <math.h>

#define SEQ 50
#define UNIT 46
#define KSZ 16
#define HCH 62              // channels we actually need: v(46) + qk(16); first 46 of Wi are dead
#define NEGBIG 1000000000000.0f

__global__ __launch_bounds__(256) void gau_kernel(
    const float* __restrict__ x,
    const float* __restrict__ mask,
    const float* __restrict__ Wi,
    const float* __restrict__ bi,
    const float* __restrict__ Wo,
    const float* __restrict__ bo,
    const float* __restrict__ sq,
    const float* __restrict__ oq,
    const float* __restrict__ sk,
    const float* __restrict__ ok,
    const float* __restrict__ Wq,
    const float* __restrict__ bq,
    float* __restrict__ out)
{
    const int b   = blockIdx.x;
    const int tid = threadIdx.x;

    __shared__ float xs[SEQ][UNIT];        // x tile; reused as out2 after phase B
    __shared__ float Wis[HCH][UNIT + 1];   // pad -> odd stride, conflict-free
    __shared__ float bis[HCH];
    __shared__ float Wos[UNIT][UNIT + 1];
    __shared__ float vs[SEQ][UNIT];
    __shared__ float qkr[SEQ][KSZ];
    __shared__ float qs[SEQ][KSZ + 1];
    __shared__ float ks[SEQ][KSZ + 1];
    __shared__ float As[SEQ][SEQ + 2];
    __shared__ float outs[SEQ][UNIT];
    __shared__ float sqv[KSZ], oqv[KSZ], skv[KSZ], okv[KSZ];
    __shared__ float Wqs[UNIT];
    __shared__ float maskr[SEQ];
    __shared__ float prob[SEQ];
    __shared__ float bq0;

    // ---- stage x, weights ----
    const float* xb = x + (size_t)b * SEQ * UNIT;
    for (int i = tid; i < SEQ * UNIT; i += 256)
        xs[i / UNIT][i % UNIT] = xb[i];
    for (int i = tid; i < HCH * UNIT; i += 256) {
        int r = i / UNIT, c = i % UNIT;
        Wis[r][c] = Wi[(size_t)(UNIT + r) * UNIT + c];
    }
    for (int i = tid; i < UNIT * UNIT; i += 256)
        Wos[i / UNIT][i % UNIT] = Wo[i];
    if (tid < HCH) bis[tid] = bi[UNIT + tid];
    if (tid < KSZ) {
        sqv[tid] = sq[tid]; oqv[tid] = oq[tid];
        skv[tid] = sk[tid]; okv[tid] = ok[tid];
    }
    if (tid < SEQ) maskr[tid] = mask[(size_t)b * SEQ + tid];
    if (tid < UNIT) Wqs[tid] = Wq[tid];
    if (tid == 0) bq0 = bq[0];
    __syncthreads();

    // ---- phase B: h = silu(x @ Wi[46:108]^T + bi) -> v, qk_raw ----
    for (int t = tid; t < SEQ * HCH; t += 256) {
        int s = t / HCH, oc = t % HCH;
        float acc = bis[oc];
        #pragma unroll
        for (int u = 0; u < UNIT; ++u)
            acc += xs[s][u] * Wis[oc][u];
        float h = acc / (1.f + __expf(-acc));   // silu
        if (oc < UNIT) vs[s][oc] = h;
        else           qkr[s][oc - UNIT] = h;
    }
    __syncthreads();

    // ---- phase C: RoPE on q = qk*sq+oq, k = qk*sk+ok ----
    for (int t = tid; t < SEQ * KSZ; t += 256) {
        int s = t / KSZ, d = t % KSZ;
        int i = d >> 1;
        float ang = (float)s * __expf(-(float)i * (logf(10000.f) / 8.f));
        float sn, cs;
        sincosf(ang, &sn, &cs);
        int   dp  = d ^ 1;
        float sgn = (d & 1) ? 1.f : -1.f;
        float qw  = qkr[s][d]  * sqv[d]  + oqv[d];
        float qwp = qkr[s][dp] * sqv[dp] + oqv[dp];
        float kw  = qkr[s][d]  * skv[d]  + okv[d];
        float kwp = qkr[s][dp] * skv[dp] + okv[dp];
        qs[s][d] = qw * cs + sgn * qwp * sn;
        ks[s][d] = kw * cs + sgn * kwp * sn;
    }
    __syncthreads();

    // ---- phase D: A = (q k^T)/4, masked ----
    for (int t = tid; t < SEQ * SEQ; t += 256) {
        int i = t / SEQ, j = t % SEQ;
        float acc = 0.f;
        #pragma unroll
        for (int d = 0; d < KSZ; ++d)
            acc += qs[i][d] * ks[j][d];
        float m = maskr[j];
        As[i][j] = acc * 0.25f * m + (1.f - m) * (-NEGBIG);
    }
    __syncthreads();

    // ---- phase E: row softmax ----
    if (tid < SEQ) {
        float mx = -INFINITY;
        for (int j = 0; j < SEQ; ++j) mx = fmaxf(mx, As[tid][j]);
        float sm = 0.f;
        for (int j = 0; j < SEQ; ++j) {
            float e = __expf(As[tid][j] - mx);
            As[tid][j] = e; sm += e;
        }
        float inv = 1.f / sm;
        for (int j = 0; j < SEQ; ++j) As[tid][j] *= inv;
    }
    __syncthreads();

    // ---- phase F: out = A @ v ----
    for (int t = tid; t < SEQ * UNIT; t += 256) {
        int i = t / UNIT, u = t % UNIT;
        float acc = 0.f;
        #pragma unroll
        for (int j = 0; j < SEQ; ++j)
            acc += As[i][j] * vs[j][u];
        outs[i][u] = acc;
    }
    __syncthreads();

    // ---- phase G: out2 = out @ Wo^T + bo  (reuse xs) ----
    float (*out2)[UNIT] = xs;
    for (int t = tid; t < SEQ * UNIT; t += 256) {
        int i = t / UNIT, o = t % UNIT;
        float acc = bo[o];
        #pragma unroll
        for (int u = 0; u < UNIT; ++u)
            acc += outs[i][u] * Wos[o][u];
        out2[i][o] = acc;
    }
    __syncthreads();

    // ---- phase H: prob = softmax(out2 @ Wq^T + bq, masked) ----
    if (tid < SEQ) {
        float acc = bq0;
        for (int o = 0; o < UNIT; ++o)
            acc += out2[tid][o] * Wqs[o];
        float m = maskr[tid];
        prob[tid] = acc * m - (1.f - m) * NEGBIG;
    }
    __syncthreads();
    if (tid == 0) {
        float mx = -INFINITY;
        for (int i = 0; i < SEQ; ++i) mx = fmaxf(mx, prob[i]);
        float sm = 0.f;
        for (int i = 0; i < SEQ; ++i) {
            float e = __expf(prob[i] - mx);
            prob[i] = e; sm += e;
        }
        float inv = 1.f / sm;
        for (int i = 0; i < SEQ; ++i) prob[i] *= inv;
    }
    __syncthreads();

    // ---- phase I: result = sum_i out2[i,:] * prob[i] ----
    for (int o = tid; o < UNIT; o += 256) {
        float acc = 0.f;
        for (int i = 0; i < SEQ; ++i)
            acc += out2[i][o] * prob[i];
        out[(size_t)b * UNIT + o] = acc;
    }
}

extern "C" void kernel_launch(void* const* d_in, const int* in_sizes, int n_in,
                              void* d_out, int out_size, void* d_ws, size_t ws_size,
                              hipStream_t stream) {
    const float* x    = (const float*)d_in[0];
    const float* mask = (const float*)d_in[1];
    const float* Wi   = (const float*)d_in[2];
    const float* bi   = (const float*)d_in[3];
    const float* Wo   = (const float*)d_in[4];
    const float* bo   = (const float*)d_in[5];
    const float* sq   = (const float*)d_in[6];
    const float* oq   = (const float*)d_in[7];
    const float* sk   = (const float*)d_in[8];
    const float* ok   = (const float*)d_in[9];
    const float* Wq   = (const float*)d_in[10];
    const float* bq   = (const float*)d_in[11];
    float* outp       = (float*)d_out;

    const int B = in_sizes[0] / (SEQ * UNIT);
    gau_kernel<<<B, 256, 0, stream>>>(x, mask, Wi, bi, Wo, bo,
                                      sq, oq, sk, ok, Wq, bq, outp);
}

// Round 2
// 1146.376 us; speedup vs baseline: 2.0597x; 2.0597x over previous
//
#include <hip/hip_runtime.h>
#include <math.h>

#define SEQ 50
#define UNIT 46
#define KSZ 16
#define NEGBIG 1000000000000.0f

// read lane `j`'s value of v (j uniform/SGPR) -> scalar usable as FMA s-operand
__device__ __forceinline__ float rl(float v, int j) {
    return __uint_as_float(__builtin_amdgcn_readlane(__float_as_uint(v), j));
}

__global__ __launch_bounds__(256, 3) void gau_kernel(
    const float* __restrict__ x,
    const float* __restrict__ mask,
    const float* __restrict__ Wi,
    const float* __restrict__ bi,
    const float* __restrict__ Wo,
    const float* __restrict__ bo,
    const float* __restrict__ sq,
    const float* __restrict__ oq,
    const float* __restrict__ sk,
    const float* __restrict__ ok,
    const float* __restrict__ Wq,
    const float* __restrict__ bq,
    float* __restrict__ out,
    int Btot)
{
    const int lane = threadIdx.x & 63;
    const int wid  = __builtin_amdgcn_readfirstlane(threadIdx.x >> 6);
    const int b    = blockIdx.x * 4 + wid;

    // per-wave LDS slice: rows stride 64 (lane in low bits -> conflict-free)
    __shared__ float smem[4][3200];
    float* sw = smem[wid];

    if (b >= Btot) return;

    const int srow = (lane < SEQ) ? lane : (SEQ - 1);   // clamp idle lanes

    // ---- load x row into registers (per-lane) ----
    float xr[UNIT];
    {
        const float* xp = x + (size_t)b * (SEQ * UNIT) + srow * UNIT;
        #pragma unroll
        for (int u = 0; u < UNIT; u += 2) {
            float2 t = *(const float2*)(xp + u);
            xr[u] = t.x; xr[u + 1] = t.y;
        }
    }
    const float mreg = mask[(size_t)b * SEQ + srow];    // lane j holds mask[j]

    // ---- phase B: h = silu(x @ Wi[46:108]^T + bi) ; weights via s_load ----
    float vreg[UNIT];
    float qk[KSZ];
    #pragma unroll
    for (int oc = 0; oc < UNIT; ++oc) {                 // v channels
        float acc = bi[UNIT + oc];
        #pragma unroll
        for (int u = 0; u < UNIT; ++u)
            acc = fmaf(xr[u], Wi[(size_t)(UNIT + oc) * UNIT + u], acc);
        vreg[oc] = acc / (1.f + __expf(-acc));
    }
    #pragma unroll
    for (int oc = 0; oc < KSZ; ++oc) {                  // qk channels
        float acc = bi[2 * UNIT + oc];
        #pragma unroll
        for (int u = 0; u < UNIT; ++u)
            acc = fmaf(xr[u], Wi[(size_t)(2 * UNIT + oc) * UNIT + u], acc);
        qk[oc] = acc / (1.f + __expf(-acc));
    }

    // ---- phase C: RoPE ----
    float q[KSZ], k[KSZ];
    {
        const float invf[8] = {1.f, 0.31622776601683794f, 0.1f, 0.031622776601683794f,
                               0.01f, 0.0031622776601683794f, 0.001f, 0.00031622776601683794f};
        #pragma unroll
        for (int d = 0; d < KSZ; d += 2) {
            float ang = (float)srow * invf[d >> 1];
            float sn, cs;
            __sincosf(ang, &sn, &cs);
            float q0 = qk[d] * sq[d] + oq[d];
            float q1 = qk[d + 1] * sq[d + 1] + oq[d + 1];
            q[d]     = q0 * cs - q1 * sn;
            q[d + 1] = q1 * cs + q0 * sn;
            float k0 = qk[d] * sk[d] + ok[d];
            float k1 = qk[d + 1] * sk[d + 1] + ok[d + 1];
            k[d]     = k0 * cs - k1 * sn;
            k[d + 1] = k1 * cs + k0 * sn;
        }
    }

    // ---- phase D: A[i][j] = q_i . k_j / 4, masked; k_j via readlane ----
    float mx = -INFINITY;
    for (int j = 0; j < SEQ; ++j) {
        float a = 0.f;
        #pragma unroll
        for (int d = 0; d < KSZ; ++d)
            a = fmaf(q[d], rl(k[d], j), a);
        float mj = rl(mreg, j);
        a = a * 0.25f * mj - (1.f - mj) * NEGBIG;
        mx = fmaxf(mx, a);
        sw[j * 64 + lane] = a;                          // A^T: conflict-free
    }

    // ---- phase F: out = softmax(A) @ v ; v_j via readlane, exp on the fly ----
    float outF[UNIT];
    #pragma unroll
    for (int u = 0; u < UNIT; ++u) outF[u] = 0.f;
    float sum = 0.f;
    for (int j = 0; j < SEQ; ++j) {
        float a = sw[j * 64 + lane];
        float p = __expf(a - mx);
        sum += p;
        #pragma unroll
        for (int u = 0; u < UNIT; ++u)
            outF[u] = fmaf(p, rl(vreg[u], j), outF[u]);
    }
    {
        float inv = 1.f / sum;
        #pragma unroll
        for (int u = 0; u < UNIT; ++u) outF[u] *= inv;
    }

    // ---- phase G: out2 = outF @ Wo^T + bo -> LDS (rotate-swizzled); hq = out2 . Wq ----
    float hq = bq[0];
    for (int o = 0; o < UNIT; ++o) {
        float acc = bo[o];
        #pragma unroll
        for (int u = 0; u < UNIT; ++u)
            acc = fmaf(outF[u], Wo[(size_t)o * UNIT + u], acc);
        sw[o * 64 + ((lane + o) & 63)] = acc;           // out2^T, swizzled
        hq = fmaf(acc, Wq[o], hq);
    }

    // ---- phase H: prob = softmax over i (cross-lane) ----
    float t = (lane < SEQ) ? (hq * mreg - (1.f - mreg) * NEGBIG) : -INFINITY;
    float m2 = t;
    #pragma unroll
    for (int off = 32; off >= 1; off >>= 1)
        m2 = fmaxf(m2, __shfl_xor(m2, off));
    float e = __expf(t - m2);
    float se = e;
    #pragma unroll
    for (int off = 32; off >= 1; off >>= 1)
        se += __shfl_xor(se, off);
    float prob = e / se;                                // lane i holds prob[i]

    // ---- phase I: out[o] = sum_i out2[i][o] * prob[i] ----
    {
        const int o = (lane < UNIT) ? lane : (UNIT - 1);
        float acc = 0.f;
        for (int i = 0; i < SEQ; ++i) {
            float pi = rl(prob, i);
            acc = fmaf(sw[o * 64 + ((i + o) & 63)], pi, acc);
        }
        if (lane < UNIT)
            out[(size_t)b * UNIT + lane] = acc;
    }
}

extern "C" void kernel_launch(void* const* d_in, const int* in_sizes, int n_in,
                              void* d_out, int out_size, void* d_ws, size_t ws_size,
                              hipStream_t stream) {
    const float* x    = (const float*)d_in[0];
    const float* mask = (const float*)d_in[1];
    const float* Wi   = (const float*)d_in[2];
    const float* bi   = (const float*)d_in[3];
    const float* Wo   = (const float*)d_in[4];
    const float* bo   = (const float*)d_in[5];
    const float* sq   = (const float*)d_in[6];
    const float* oq   = (const float*)d_in[7];
    const float* sk   = (const float*)d_in[8];
    const float* ok   = (const float*)d_in[9];
    const float* Wq   = (const float*)d_in[10];
    const float* bq   = (const float*)d_in[11];
    float* outp       = (float*)d_out;

    const int B = in_sizes[0] / (SEQ * UNIT);
    const int blocks = (B + 3) / 4;
    gau_kernel<<<blocks, 256, 0, stream>>>(x, mask, Wi, bi, Wo, bo,
                                           sq, oq, sk, ok, Wq, bq, outp, B);
}

// Round 3
// 1136.340 us; speedup vs baseline: 2.0779x; 1.0088x over previous
//
#include <hip/hip_runtime.h>
#include <hip/hip_fp16.h>
#include <math.h>

#define SEQ 50
#define UNIT 46
#define KSZ 16
#define NEGBIG 1000000000000.0f

// read lane j's value (j wave-uniform) -> SGPR, usable as scalar FMA operand
__device__ __forceinline__ float rlf(float v, int j) {
    return __uint_as_float(__builtin_amdgcn_readlane(__float_as_uint(v), j));
}
__device__ __forceinline__ unsigned rlu(unsigned v, int j) {
    return __builtin_amdgcn_readlane(v, j);
}

__global__ __launch_bounds__(256, 3) void gau_kernel(
    const float* __restrict__ x,
    const float* __restrict__ mask,
    const float* __restrict__ Wi,
    const float* __restrict__ bi,
    const float* __restrict__ Wo,
    const float* __restrict__ bo,
    const float* __restrict__ sq,
    const float* __restrict__ oq,
    const float* __restrict__ sk,
    const float* __restrict__ ok,
    const float* __restrict__ Wq,
    const float* __restrict__ bq,
    float* __restrict__ out)
{
    const int lane = threadIdx.x & 63;
    const int wid  = __builtin_amdgcn_readfirstlane(threadIdx.x >> 6);
    const int b    = blockIdx.x * 4 + wid;

    // 2560 floats per wave = 40KB/block -> 4 blocks/CU LDS-wise
    __shared__ float smem[4][2560];
    float* sw = smem[wid];

    const int srow = (lane < SEQ) ? lane : (SEQ - 1);   // clamp idle lanes
    const int colA = (lane < SEQ + 1) ? lane : SEQ;     // min(lane,50): dump col
    const int rowG = colA;                              // dump row 50 for out2

    // ---- load x row, pack to fp16 pairs (23 regs) ----
    unsigned xh[UNIT / 2];
    {
        const float* xp = x + (size_t)b * (SEQ * UNIT) + srow * UNIT;
        #pragma unroll
        for (int u = 0; u < UNIT; u += 2) {
            float2 t = *(const float2*)(xp + u);
            xh[u >> 1] = __builtin_bit_cast(unsigned, __floats2half2_rn(t.x, t.y));
        }
    }
    const float mreg = mask[(size_t)b * SEQ + srow];    // lane j holds mask[j]

    // ---- phase B: h = silu(x @ Wi[46:108]^T + bi); weights via s_load ----
    unsigned vpk[UNIT / 2];                             // v packed fp16 (23 regs)
    float qk[KSZ];
    #pragma unroll
    for (int oc = 0; oc < UNIT; oc += 2) {              // v channels, pack pairs
        float acc0 = bi[UNIT + oc];
        float acc1 = bi[UNIT + oc + 1];
        #pragma unroll
        for (int u2 = 0; u2 < UNIT / 2; ++u2) {
            __half2 hx = __builtin_bit_cast(__half2, xh[u2]);
            float xl = __low2float(hx), xhh = __high2float(hx);
            acc0 = fmaf(xl,  Wi[(size_t)(UNIT + oc) * UNIT + 2 * u2],     acc0);
            acc0 = fmaf(xhh, Wi[(size_t)(UNIT + oc) * UNIT + 2 * u2 + 1], acc0);
            acc1 = fmaf(xl,  Wi[(size_t)(UNIT + oc + 1) * UNIT + 2 * u2],     acc1);
            acc1 = fmaf(xhh, Wi[(size_t)(UNIT + oc + 1) * UNIT + 2 * u2 + 1], acc1);
        }
        float h0 = acc0 / (1.f + __expf(-acc0));
        float h1 = acc1 / (1.f + __expf(-acc1));
        vpk[oc >> 1] = __builtin_bit_cast(unsigned, __floats2half2_rn(h0, h1));
    }
    #pragma unroll
    for (int oc = 0; oc < KSZ; ++oc) {                  // qk channels (fp32)
        float acc = bi[2 * UNIT + oc];
        #pragma unroll
        for (int u2 = 0; u2 < UNIT / 2; ++u2) {
            __half2 hx = __builtin_bit_cast(__half2, xh[u2]);
            acc = fmaf(__low2float(hx),  Wi[(size_t)(2 * UNIT + oc) * UNIT + 2 * u2],     acc);
            acc = fmaf(__high2float(hx), Wi[(size_t)(2 * UNIT + oc) * UNIT + 2 * u2 + 1], acc);
        }
        qk[oc] = acc / (1.f + __expf(-acc));
    }

    // ---- phase C: RoPE (q,k fp32) ----
    float q[KSZ], k[KSZ];
    {
        const float invf[8] = {1.f, 0.31622776601683794f, 0.1f, 0.031622776601683794f,
                               0.01f, 0.0031622776601683794f, 0.001f, 0.00031622776601683794f};
        #pragma unroll
        for (int d = 0; d < KSZ; d += 2) {
            float ang = (float)srow * invf[d >> 1];
            float sn, cs;
            __sincosf(ang, &sn, &cs);
            float q0 = qk[d] * sq[d] + oq[d];
            float q1 = qk[d + 1] * sq[d + 1] + oq[d + 1];
            q[d]     = q0 * cs - q1 * sn;
            q[d + 1] = q1 * cs + q0 * sn;
            float k0 = qk[d] * sk[d] + ok[d];
            float k1 = qk[d + 1] * sk[d + 1] + ok[d + 1];
            k[d]     = k0 * cs - k1 * sn;
            k[d + 1] = k1 * cs + k0 * sn;
        }
    }

    // ---- phase D: A[i][j] = q_i . k_j / 4, masked; k_j via readlane ----
    // element (i,j) stored at sw[j*51 + i] (stride 51, dump col 50)
    float mx = -INFINITY;
    for (int j = 0; j < SEQ; ++j) {
        float a = 0.f;
        #pragma unroll
        for (int d = 0; d < KSZ; ++d)
            a = fmaf(q[d], rlf(k[d], j), a);
        float mj = rlf(mreg, j);
        a = a * 0.25f * mj - (1.f - mj) * NEGBIG;
        mx = fmaxf(mx, a);
        sw[j * 51 + colA] = a;
    }

    // ---- phase F: out = softmax(A) @ v ; v_j via packed readlane ----
    float outF[UNIT];
    #pragma unroll
    for (int u = 0; u < UNIT; ++u) outF[u] = 0.f;
    float sum = 0.f;
    for (int j = 0; j < SEQ; ++j) {
        float a = sw[j * 51 + colA];
        float p = __expf(a - mx);
        sum += p;
        #pragma unroll
        for (int u2 = 0; u2 < UNIT / 2; ++u2) {
            __half2 hv = __builtin_bit_cast(__half2, rlu(vpk[u2], j));
            outF[2 * u2]     = fmaf(p, __low2float(hv),  outF[2 * u2]);
            outF[2 * u2 + 1] = fmaf(p, __high2float(hv), outF[2 * u2 + 1]);
        }
    }
    {
        float inv = 1.f / sum;
        #pragma unroll
        for (int u = 0; u < UNIT; ++u) outF[u] *= inv;
    }

    // ---- phase G: out2 = outF @ Wo^T + bo -> LDS [i][o] stride 47; hq = out2.Wq ----
    float hq = bq[0];
    #pragma unroll
    for (int o = 0; o < UNIT; ++o) {
        float acc = bo[o];
        #pragma unroll
        for (int u = 0; u < UNIT; ++u)
            acc = fmaf(outF[u], Wo[(size_t)o * UNIT + u], acc);
        sw[rowG * 47 + o] = acc;
        hq = fmaf(acc, Wq[o], hq);
    }

    // ---- phase H: prob = softmax over i (cross-lane) ----
    float t = (lane < SEQ) ? (hq * mreg - (1.f - mreg) * NEGBIG) : -INFINITY;
    float m2 = t;
    #pragma unroll
    for (int off = 32; off >= 1; off >>= 1)
        m2 = fmaxf(m2, __shfl_xor(m2, off));
    float e = __expf(t - m2);
    float se = e;
    #pragma unroll
    for (int off = 32; off >= 1; off >>= 1)
        se += __shfl_xor(se, off);
    float prob = e / se;                                // lane i holds prob[i]

    // ---- phase I: out[o] = sum_i out2[i][o] * prob[i] ----
    {
        float acc = 0.f;
        for (int i = 0; i < SEQ; ++i) {
            float pi = rlf(prob, i);
            acc = fmaf(sw[i * 47 + lane], pi, acc);     // lanes consecutive: conflict-free
        }
        if (lane < UNIT)
            out[(size_t)b * UNIT + lane] = acc;
    }
}

extern "C" void kernel_launch(void* const* d_in, const int* in_sizes, int n_in,
                              void* d_out, int out_size, void* d_ws, size_t ws_size,
                              hipStream_t stream) {
    const float* x    = (const float*)d_in[0];
    const float* mask = (const float*)d_in[1];
    const float* Wi   = (const float*)d_in[2];
    const float* bi   = (const float*)d_in[3];
    const float* Wo   = (const float*)d_in[4];
    const float* bo   = (const float*)d_in[5];
    const float* sq   = (const float*)d_in[6];
    const float* oq   = (const float*)d_in[7];
    const float* sk   = (const float*)d_in[8];
    const float* ok   = (const float*)d_in[9];
    const float* Wq   = (const float*)d_in[10];
    const float* bq   = (const float*)d_in[11];
    float* outp       = (float*)d_out;

    const int B = in_sizes[0] / (SEQ * UNIT);
    const int blocks = (B + 3) / 4;
    gau_kernel<<<blocks, 256, 0, stream>>>(x, mask, Wi, bi, Wo, bo,
                                           sq, oq, sk, ok, Wq, bq, outp);
}

// Round 5
// 337.815 us; speedup vs baseline: 6.9897x; 3.3638x over previous
//
#include <hip/hip_runtime.h>
#include <math.h>

#define SEQ 50
#define UNITD 46
#define NEGBIG 1000000000000.0f

typedef _Float16 f16;
typedef f16 f16x4 __attribute__((ext_vector_type(4)));
typedef f16 f16x8 __attribute__((ext_vector_type(8)));
typedef float f32x4 __attribute__((ext_vector_type(4)));

__device__ __forceinline__ float rcpf(float x) { return __builtin_amdgcn_rcpf(x); }

// byte offset into a 128B-row LDS tile, XOR-swizzled to break b128 bank conflicts
__device__ __forceinline__ int swz128(int row, int colbyte) {
    return row * 128 + (colbyte ^ ((row & 7) << 4));
}

// per-wave arena layout (bytes):
//   [0,8192)      P  [64][64] f16 swizzled; reused as out_lds after PV reads
//   [8192,14336)  V^T [48][64] f16 swizzled (row=u, col=seq)
//   [14336,16896) Q  [64 rows][20 halves]
//   [16896,19456) K  [64 rows][20 halves]
//   [19456,19712) M  [64] f32 (mask, zero-padded)
#define ARENA 19712

__global__ __launch_bounds__(256, 2) void gau_kernel(
    const float* __restrict__ x,
    const float* __restrict__ mask,
    const float* __restrict__ Wi,
    const float* __restrict__ bi,
    const float* __restrict__ Wo,
    const float* __restrict__ bo,
    const float* __restrict__ sq,
    const float* __restrict__ oq,
    const float* __restrict__ sk,
    const float* __restrict__ ok,
    const float* __restrict__ Wq,
    const float* __restrict__ bq,
    float* __restrict__ out,
    int Btot)
{
    const int lane = threadIdx.x & 63;
    const int wid  = threadIdx.x >> 6;
    const int b    = blockIdx.x * 4 + wid;
    const int g    = lane >> 4;      // 16-lane group 0..3
    const int t    = lane & 15;

    __shared__ __align__(16) char smem[4 * ARENA];
    char* wa = smem + wid * ARENA;
    char*  Pb = wa;                       // P / out tile (swizzled, 128B rows)
    char*  Vb = wa + 8192;                // V^T tile (swizzled, 128B rows)
    f16*   Q  = (f16*)(wa + 14336);       // [64][20]
    f16*   K  = (f16*)(wa + 16896);       // [64][20]
    float* M  = (float*)(wa + 19456);     // [64]

    if (b >= Btot) return;

    // ---- mask -> LDS (zero-padded to 64) ----
    M[lane] = (lane < SEQ) ? mask[(size_t)b * SEQ + lane] : 0.f;

    // ================= phase B: h = silu(x @ Wi[46:108]^T + bi) =================
    // Wi B-fragments: B[k=u][n=ch], n = t + 16*nt, k = 32*kt + 8*g + jj
    f16x8 bfW[4][2];
    float biv[4];
    #pragma unroll
    for (int nt = 0; nt < 4; ++nt) {
        int c = t + 16 * nt;
        bool cok = c < 62;
        const float* wr = Wi + (size_t)(UNITD + (cok ? c : 0)) * UNITD;
        biv[nt] = cok ? bi[UNITD + c] : 0.f;
        #pragma unroll
        for (int kt = 0; kt < 2; ++kt) {
            f16x8 f;
            #pragma unroll
            for (int jj = 0; jj < 8; jj += 2) {
                int u = 32 * kt + 8 * g + jj;
                float lo = 0.f, hi = 0.f;
                if (cok && u < UNITD) { float2 w = *(const float2*)(wr + u); lo = w.x; hi = w.y; }
                f[jj] = (f16)lo; f[jj + 1] = (f16)hi;
            }
            bfW[nt][kt] = f;
        }
    }

    f32x4 hB[4][4];
    #pragma unroll
    for (int mt = 0; mt < 4; ++mt)
        #pragma unroll
        for (int nt = 0; nt < 4; ++nt) {
            f32x4 c; c[0] = biv[nt]; c[1] = biv[nt]; c[2] = biv[nt]; c[3] = biv[nt];
            hB[mt][nt] = c;
        }

    const float* xb = x + (size_t)b * (SEQ * UNITD);
    #pragma unroll
    for (int mt = 0; mt < 4; ++mt) {
        int row = 16 * mt + t; if (row > SEQ - 1) row = SEQ - 1;   // clamp pad rows
        const float* xr = xb + row * UNITD;
        #pragma unroll
        for (int kt = 0; kt < 2; ++kt) {
            f16x8 ax;
            #pragma unroll
            for (int jj = 0; jj < 8; jj += 2) {
                int u = 32 * kt + 8 * g + jj;
                float lo = 0.f, hi = 0.f;
                if (u < UNITD) { float2 w = *(const float2*)(xr + u); lo = w.x; hi = w.y; }
                ax[jj] = (f16)lo; ax[jj + 1] = (f16)hi;
            }
            #pragma unroll
            for (int nt = 0; nt < 4; ++nt)
                hB[mt][nt] = __builtin_amdgcn_mfma_f32_16x16x32_f16(ax, bfW[nt][kt], hB[mt][nt], 0, 0, 0);
        }
    }

    // ---- silu; v -> V^T LDS (f16); qk channels kept in regs ----
    // h C-layout: row(seq) = 4g + r + 16mt, col(ch) = t + 16nt
    float qkv[4][4];                       // [mt][r] value at this lane's d
    #pragma unroll
    for (int mt = 0; mt < 4; ++mt) {
        float s2[4], s3[4];
        #pragma unroll
        for (int nt = 0; nt < 4; ++nt) {
            float sl[4];
            #pragma unroll
            for (int r = 0; r < 4; ++r) {
                float h = hB[mt][nt][r];
                sl[r] = h * rcpf(1.f + __expf(-h));
            }
            int ucol = t + 16 * nt;
            if (nt < 3 && ucol < UNITD) {
                f16x4 pv;
                #pragma unroll
                for (int r = 0; r < 4; ++r) pv[r] = (f16)sl[r];
                *(f16x4*)(Vb + swz128(ucol, (16 * mt + 4 * g) * 2)) = pv;
            }
            if (nt == 2) { s2[0]=sl[0]; s2[1]=sl[1]; s2[2]=sl[2]; s2[3]=sl[3]; }
            if (nt == 3) { s3[0]=sl[0]; s3[1]=sl[1]; s3[2]=sl[2]; s3[3]=sl[3]; }
        }
        #pragma unroll
        for (int r = 0; r < 4; ++r) qkv[mt][r] = (t >= 14) ? s2[r] : s3[r];
    }

    // ================= phase C: RoPE; q,k -> LDS [seq][d] f16 =================
    {
        int d = (t >= 14) ? (t - 14) : (t + 2);            // this lane's channel
        float invf = __expf(-(float)(d >> 1) * 1.1512925464970229f); // ln(1e4)/8
        float sgn  = (d & 1) ? 1.f : -1.f;
        float sqd = sq[d], oqd = oq[d], skd = sk[d], okd = ok[d];
        #pragma unroll
        for (int mt = 0; mt < 4; ++mt)
            #pragma unroll
            for (int r = 0; r < 4; ++r) {
                int seq = 16 * mt + 4 * g + r;
                float qv = qkv[mt][r] * sqd + oqd;
                float kv = qkv[mt][r] * skd + okd;
                float qp = __shfl_xor(qv, 1);
                float kp = __shfl_xor(kv, 1);
                float sn, cs;
                __sincosf((float)seq * invf, &sn, &cs);
                Q[seq * 20 + d] = (f16)(qv * cs + sgn * qp * sn);
                K[seq * 20 + d] = (f16)(kv * cs + sgn * kp * sn);
            }
    }

    // ================= phase D: P^T = (K Q^T)/4, masked, softmax =================
    // swapped operands: A = k (M=j), B = q^T (N=i)  ->  C[j][i]
    f16x4 ak[4], bq_[4];
    #pragma unroll
    for (int m4 = 0; m4 < 4; ++m4) ak[m4]  = *(f16x4*)((char*)K + (16 * m4 + t) * 40 + 8 * g);
    #pragma unroll
    for (int n4 = 0; n4 < 4; ++n4) bq_[n4] = *(f16x4*)((char*)Q + (16 * n4 + t) * 40 + 8 * g);

    f32x4 pT[4][4];
    #pragma unroll
    for (int m4 = 0; m4 < 4; ++m4)
        #pragma unroll
        for (int n4 = 0; n4 < 4; ++n4) {
            f32x4 z; z[0]=0.f; z[1]=0.f; z[2]=0.f; z[3]=0.f;
            pT[m4][n4] = __builtin_amdgcn_mfma_f32_16x16x16f16(ak[m4], bq_[n4], z, 0, 0, 0);
        }

    float mjv[4][4];
    #pragma unroll
    for (int m4 = 0; m4 < 4; ++m4)
        #pragma unroll
        for (int r = 0; r < 4; ++r) mjv[m4][r] = M[16 * m4 + 4 * g + r];

    // row softmax (over j = 4g+r+16m4: in-lane + shfl over g), normalize, pack f16
    #pragma unroll
    for (int n4 = 0; n4 < 4; ++n4) {
        float a_[4][4]; float mx = -INFINITY;
        #pragma unroll
        for (int m4 = 0; m4 < 4; ++m4)
            #pragma unroll
            for (int r = 0; r < 4; ++r) {
                float mj = mjv[m4][r];
                float av = pT[m4][n4][r] * 0.25f * mj - (1.f - mj) * NEGBIG;
                a_[m4][r] = av; mx = fmaxf(mx, av);
            }
        mx = fmaxf(mx, __shfl_xor(mx, 16)); mx = fmaxf(mx, __shfl_xor(mx, 32));
        float sm = 0.f;
        #pragma unroll
        for (int m4 = 0; m4 < 4; ++m4)
            #pragma unroll
            for (int r = 0; r < 4; ++r) { float e = __expf(a_[m4][r] - mx); a_[m4][r] = e; sm += e; }
        sm += __shfl_xor(sm, 16); sm += __shfl_xor(sm, 32);
        float inv = rcpf(sm);
        int i = t + 16 * n4;
        #pragma unroll
        for (int m4 = 0; m4 < 4; ++m4) {
            f16x4 pk;
            #pragma unroll
            for (int r = 0; r < 4; ++r) pk[r] = (f16)(a_[m4][r] * inv);
            *(f16x4*)(Pb + swz128(i, (16 * m4 + 4 * g) * 2)) = pk;   // P[i][j]
        }
    }

    // ================= phase F: out = P @ v =================
    f16x8 bv[3][2];
    #pragma unroll
    for (int nt = 0; nt < 3; ++nt)
        #pragma unroll
        for (int kt = 0; kt < 2; ++kt)
            bv[nt][kt] = *(f16x8*)(Vb + swz128(t + 16 * nt, (32 * kt + 8 * g) * 2));

    f32x4 oA[4][3];
    #pragma unroll
    for (int mt = 0; mt < 4; ++mt)
        #pragma unroll
        for (int nt = 0; nt < 3; ++nt) { f32x4 z; z[0]=0.f; z[1]=0.f; z[2]=0.f; z[3]=0.f; oA[mt][nt] = z; }

    #pragma unroll
    for (int mt = 0; mt < 4; ++mt)
        #pragma unroll
        for (int kt = 0; kt < 2; ++kt) {
            f16x8 ap = *(f16x8*)(Pb + swz128(16 * mt + t, (32 * kt + 8 * g) * 2));
            #pragma unroll
            for (int nt = 0; nt < 3; ++nt)
                oA[mt][nt] = __builtin_amdgcn_mfma_f32_16x16x32_f16(ap, bv[nt][kt], oA[mt][nt], 0, 0, 0);
        }

    // out -> out_lds (reuse P region): out[i = 4g+r+16mt][u = t+16nt], f16
    #pragma unroll
    for (int mt = 0; mt < 4; ++mt)
        #pragma unroll
        for (int nt = 0; nt < 3; ++nt) {
            int u = t + 16 * nt;
            if (u < UNITD) {
                #pragma unroll
                for (int r = 0; r < 4; ++r)
                    *(f16*)(Pb + swz128(4 * g + r + 16 * mt, u * 2)) = (f16)oA[mt][nt][r];
            }
        }

    // ================= phase G: out2^T = Wo @ out^T (+bo) =================
    f16x8 aw[3][2];
    #pragma unroll
    for (int mo = 0; mo < 3; ++mo) {
        int o = 16 * mo + t; bool ook = (o < UNITD);
        const float* wr = Wo + (size_t)(ook ? o : 0) * UNITD;
        #pragma unroll
        for (int kt = 0; kt < 2; ++kt) {
            f16x8 f;
            #pragma unroll
            for (int jj = 0; jj < 8; jj += 2) {
                int u = 32 * kt + 8 * g + jj;
                float lo = 0.f, hi = 0.f;
                if (ook && u < UNITD) { float2 w = *(const float2*)(wr + u); lo = w.x; hi = w.y; }
                f[jj] = (f16)lo; f[jj + 1] = (f16)hi;
            }
            aw[mo][kt] = f;
        }
    }

    f32x4 o2[3][4];
    #pragma unroll
    for (int mo = 0; mo < 3; ++mo)
        #pragma unroll
        for (int n4 = 0; n4 < 4; ++n4) { f32x4 z; z[0]=0.f; z[1]=0.f; z[2]=0.f; z[3]=0.f; o2[mo][n4] = z; }

    #pragma unroll
    for (int n4 = 0; n4 < 4; ++n4)
        #pragma unroll
        for (int kt = 0; kt < 2; ++kt) {
            f16x8 bo_ = *(f16x8*)(Pb + swz128(t + 16 * n4, (32 * kt + 8 * g) * 2));
            #pragma unroll
            for (int mo = 0; mo < 3; ++mo)
                o2[mo][n4] = __builtin_amdgcn_mfma_f32_16x16x32_f16(aw[mo][kt], bo_, o2[mo][n4], 0, 0, 0);
        }

    // +bo ; per-slot Wq
    float bov[3][4], wqv[3][4];
    #pragma unroll
    for (int mo = 0; mo < 3; ++mo)
        #pragma unroll
        for (int r = 0; r < 4; ++r) {
            int o = 16 * mo + 4 * g + r; bool ok2 = (o < UNITD);
            bov[mo][r] = ok2 ? bo[o] : 0.f;
            wqv[mo][r] = ok2 ? Wq[o] : 0.f;
        }
    #pragma unroll
    for (int mo = 0; mo < 3; ++mo)
        #pragma unroll
        for (int n4 = 0; n4 < 4; ++n4)
            #pragma unroll
            for (int r = 0; r < 4; ++r) o2[mo][n4][r] += bov[mo][r];

    // ================= phase H: prob = softmax_i(out2 . Wq + bq, masked) =================
    float bq0 = bq[0];
    float tv[4]; float mx2 = -INFINITY;
    #pragma unroll
    for (int n4 = 0; n4 < 4; ++n4) {
        float s = 0.f;
        #pragma unroll
        for (int mo = 0; mo < 3; ++mo)
            #pragma unroll
            for (int r = 0; r < 4; ++r) s += o2[mo][n4][r] * wqv[mo][r];
        s += __shfl_xor(s, 16); s += __shfl_xor(s, 32);
        float hq = s + bq0;
        float mi = M[t + 16 * n4];
        tv[n4] = hq * mi - (1.f - mi) * NEGBIG;
        mx2 = fmaxf(mx2, tv[n4]);
    }
    #pragma unroll
    for (int off = 1; off <= 8; off <<= 1) mx2 = fmaxf(mx2, __shfl_xor(mx2, off));
    float sm2 = 0.f;
    #pragma unroll
    for (int n4 = 0; n4 < 4; ++n4) { float e = __expf(tv[n4] - mx2); tv[n4] = e; sm2 += e; }
    #pragma unroll
    for (int off = 1; off <= 8; off <<= 1) sm2 += __shfl_xor(sm2, off);
    float inv2 = rcpf(sm2);

    // ================= phase I: result[o] = sum_i out2[i][o] * prob[i] =================
    #pragma unroll
    for (int mo = 0; mo < 3; ++mo) {
        float racc[4];
        #pragma unroll
        for (int r = 0; r < 4; ++r) {
            float a = 0.f;
            #pragma unroll
            for (int n4 = 0; n4 < 4; ++n4) a += o2[mo][n4][r] * tv[n4];
            racc[r] = a;
        }
        #pragma unroll
        for (int off = 1; off <= 8; off <<= 1)
            #pragma unroll
            for (int r = 0; r < 4; ++r) racc[r] += __shfl_xor(racc[r], off);
        if (t == 0) {
            #pragma unroll
            for (int r = 0; r < 4; ++r) {
                int o = 16 * mo + 4 * g + r;
                if (o < UNITD) out[(size_t)b * UNITD + o] = racc[r] * inv2;
            }
        }
    }
}

extern "C" void kernel_launch(void* const* d_in, const int* in_sizes, int n_in,
                              void* d_out, int out_size, void* d_ws, size_t ws_size,
                              hipStream_t stream) {
    const float* x    = (const float*)d_in[0];
    const float* mask = (const float*)d_in[1];
    const float* Wi   = (const float*)d_in[2];
    const float* bi   = (const float*)d_in[3];
    const float* Wo   = (const float*)d_in[4];
    const float* bo   = (const float*)d_in[5];
    const float* sq   = (const float*)d_in[6];
    const float* oq   = (const float*)d_in[7];
    const float* sk   = (const float*)d_in[8];
    const float* ok   = (const float*)d_in[9];
    const float* Wq   = (const float*)d_in[10];
    const float* bq   = (const float*)d_in[11];
    float* outp       = (float*)d_out;

    const int B = in_sizes[0] / (SEQ * UNITD);
    const int blocks = (B + 3) / 4;
    gau_kernel<<<blocks, 256, 0, stream>>>(x, mask, Wi, bi, Wo, bo,
                                           sq, oq, sk, ok, Wq, bq, outp, B);
}

// Round 6
// 202.759 us; speedup vs baseline: 11.6455x; 1.6661x over previous
//
#include <hip/hip_runtime.h>
#include <math.h>

#define SEQ 50
#define UNITD 46
#define NEGBIG 1000000000000.0f

typedef _Float16 f16;
typedef f16 f16x4 __attribute__((ext_vector_type(4)));
typedef f16 f16x8 __attribute__((ext_vector_type(8)));
typedef float f32x4 __attribute__((ext_vector_type(4)));

__device__ __forceinline__ float rcpf(float x) { return __builtin_amdgcn_rcpf(x); }

// ---- per-wave arena (bytes) ----
// [0,6400)      P tile [50 rows][128B f16] swizzled; Q/K overlay it early; out tile reuses it later
// [6400,12544)  V^T [48 rows][128B f16] swizzled (row=u, col=seq)
// [12544,12800) M [64] f32 (mask, zero-padded)
#define ARENA 12800
#define QOFF 0
#define KOFF 2560
#define VOFF 6400
#define MOFF 12544

__device__ __forceinline__ int swzP(int row, int colbyte) {
    return row * 128 + (colbyte ^ ((row & 7) << 4));
}
__device__ __forceinline__ int swzV(int row, int colbyte) {
    return VOFF + row * 128 + (colbyte ^ ((row & 7) << 4));
}

// ---------- prologue: build f16 weight fragments in ws ----------
// ws layout (f16x8 units): [0,512)  Wi frags, idx = (nt*2+kt)*64 + lane
//                          [512,896) Wo frags, idx = 512 + (mo*2+kt)*64 + lane
__global__ void prep_kernel(const float* __restrict__ Wi,
                            const float* __restrict__ Wo,
                            f16x8* __restrict__ ws)
{
    const int lane = threadIdx.x & 63;
    const int g = lane >> 4, t = lane & 15;
    #pragma unroll
    for (int nt = 0; nt < 4; ++nt) {
        int c = t + 16 * nt; bool cok = c < 62;
        const float* wr = Wi + (size_t)(UNITD + (cok ? c : 0)) * UNITD;
        #pragma unroll
        for (int kt = 0; kt < 2; ++kt) {
            f16x8 f;
            #pragma unroll
            for (int jj = 0; jj < 8; ++jj) {
                int u = 32 * kt + 8 * g + jj;
                f[jj] = (f16)((cok && u < UNITD) ? wr[u] : 0.f);
            }
            ws[(nt * 2 + kt) * 64 + lane] = f;
        }
    }
    #pragma unroll
    for (int mo = 0; mo < 3; ++mo) {
        int o = 16 * mo + t; bool ook = o < UNITD;
        const float* wr = Wo + (size_t)(ook ? o : 0) * UNITD;
        #pragma unroll
        for (int kt = 0; kt < 2; ++kt) {
            f16x8 f;
            #pragma unroll
            for (int jj = 0; jj < 8; ++jj) {
                int u = 32 * kt + 8 * g + jj;
                f[jj] = (f16)((ook && u < UNITD) ? wr[u] : 0.f);
            }
            ws[512 + (mo * 2 + kt) * 64 + lane] = f;
        }
    }
}

__global__ __launch_bounds__(256, 3) void gau_kernel(
    const float* __restrict__ x,
    const float* __restrict__ mask,
    const f16x8* __restrict__ wf,      // precomputed fragments
    const float* __restrict__ bi,
    const float* __restrict__ bo,
    const float* __restrict__ sq,
    const float* __restrict__ oq,
    const float* __restrict__ sk,
    const float* __restrict__ ok,
    const float* __restrict__ Wq,
    const float* __restrict__ bq,
    float* __restrict__ out,
    int Btot)
{
    const int lane = threadIdx.x & 63;
    const int wid  = threadIdx.x >> 6;
    const int b    = blockIdx.x * 4 + wid;
    const int g    = lane >> 4;
    const int t    = lane & 15;

    __shared__ __align__(16) char smem[4 * ARENA];
    char* wa = smem + wid * ARENA;
    float* M = (float*)(wa + MOFF);

    if (b >= Btot) return;

    M[lane] = (lane < SEQ) ? mask[(size_t)b * SEQ + lane] : 0.f;

    // ================= phase B: h = silu(x @ Wi[46:108]^T + bi) =================
    f16x8 bfW[4][2];
    float biv[4];
    #pragma unroll
    for (int nt = 0; nt < 4; ++nt) {
        int c = t + 16 * nt;
        biv[nt] = (c < 62) ? bi[UNITD + c] : 0.f;
        #pragma unroll
        for (int kt = 0; kt < 2; ++kt)
            bfW[nt][kt] = wf[(nt * 2 + kt) * 64 + lane];
    }

    f32x4 hB[4][4];
    #pragma unroll
    for (int mt = 0; mt < 4; ++mt)
        #pragma unroll
        for (int nt = 0; nt < 4; ++nt) {
            f32x4 c; c[0] = biv[nt]; c[1] = biv[nt]; c[2] = biv[nt]; c[3] = biv[nt];
            hB[mt][nt] = c;
        }

    const float* xb = x + (size_t)b * (SEQ * UNITD);
    #pragma unroll
    for (int mt = 0; mt < 4; ++mt) {
        int row = 16 * mt + t; if (row > SEQ - 1) row = SEQ - 1;   // clamp pad rows
        const float* xr = xb + row * UNITD;
        #pragma unroll
        for (int kt = 0; kt < 2; ++kt) {
            f16x8 ax;
            #pragma unroll
            for (int jj = 0; jj < 8; jj += 2) {
                int u = 32 * kt + 8 * g + jj;
                float lo = 0.f, hi = 0.f;
                if (u < UNITD) { float2 w = *(const float2*)(xr + u); lo = w.x; hi = w.y; }
                ax[jj] = (f16)lo; ax[jj + 1] = (f16)hi;
            }
            #pragma unroll
            for (int nt = 0; nt < 4; ++nt)
                hB[mt][nt] = __builtin_amdgcn_mfma_f32_16x16x32_f16(ax, bfW[nt][kt], hB[mt][nt], 0, 0, 0);
        }
    }

    // ---- silu; v -> V^T LDS (f16); qk channels kept in regs ----
    float qkv[4][4];
    #pragma unroll
    for (int mt = 0; mt < 4; ++mt) {
        float s2[4], s3[4];
        #pragma unroll
        for (int nt = 0; nt < 4; ++nt) {
            float sl[4];
            #pragma unroll
            for (int r = 0; r < 4; ++r) {
                float h = hB[mt][nt][r];
                sl[r] = h * rcpf(1.f + __expf(-h));
            }
            int ucol = t + 16 * nt;
            if (nt < 3 && ucol < UNITD) {
                f16x4 pv;
                #pragma unroll
                for (int r = 0; r < 4; ++r) pv[r] = (f16)sl[r];
                *(f16x4*)(wa + swzV(ucol, (16 * mt + 4 * g) * 2)) = pv;
            }
            if (nt == 2) { s2[0]=sl[0]; s2[1]=sl[1]; s2[2]=sl[2]; s2[3]=sl[3]; }
            if (nt == 3) { s3[0]=sl[0]; s3[1]=sl[1]; s3[2]=sl[2]; s3[3]=sl[3]; }
        }
        #pragma unroll
        for (int r = 0; r < 4; ++r) qkv[mt][r] = (t >= 14) ? s2[r] : s3[r];
    }

    // ================= phase C: RoPE; q,k -> LDS (overlaying P region) =================
    {
        f16* Q = (f16*)(wa + QOFF);
        f16* K = (f16*)(wa + KOFF);
        int d = (t >= 14) ? (t - 14) : (t + 2);
        float invf = __expf(-(float)(d >> 1) * 1.1512925464970229f); // ln(1e4)/8
        float sgn  = (d & 1) ? 1.f : -1.f;
        float sqd = sq[d], oqd = oq[d], skd = sk[d], okd = ok[d];
        #pragma unroll
        for (int mt = 0; mt < 4; ++mt)
            #pragma unroll
            for (int r = 0; r < 4; ++r) {
                int seq = 16 * mt + 4 * g + r;
                float qv = qkv[mt][r] * sqd + oqd;
                float kv = qkv[mt][r] * skd + okd;
                float qp = __shfl_xor(qv, 1);
                float kp = __shfl_xor(kv, 1);
                float sn, cs;
                __sincosf((float)seq * invf, &sn, &cs);
                Q[seq * 20 + d] = (f16)(qv * cs + sgn * qp * sn);
                K[seq * 20 + d] = (f16)(kv * cs + sgn * kp * sn);
            }
    }

    // ================= phase D: P^T = (K Q^T)/4, masked, softmax =================
    f16x4 ak[4], bq_[4];
    #pragma unroll
    for (int m4 = 0; m4 < 4; ++m4) ak[m4]  = *(f16x4*)(wa + KOFF + (16 * m4 + t) * 40 + 8 * g);
    #pragma unroll
    for (int n4 = 0; n4 < 4; ++n4) bq_[n4] = *(f16x4*)(wa + QOFF + (16 * n4 + t) * 40 + 8 * g);

    f32x4 pT[4][4];
    #pragma unroll
    for (int m4 = 0; m4 < 4; ++m4)
        #pragma unroll
        for (int n4 = 0; n4 < 4; ++n4) {
            f32x4 z; z[0]=0.f; z[1]=0.f; z[2]=0.f; z[3]=0.f;
            pT[m4][n4] = __builtin_amdgcn_mfma_f32_16x16x16f16(ak[m4], bq_[n4], z, 0, 0, 0);
        }

    float mjv[4][4];
    #pragma unroll
    for (int m4 = 0; m4 < 4; ++m4)
        #pragma unroll
        for (int r = 0; r < 4; ++r) mjv[m4][r] = M[16 * m4 + 4 * g + r];

    // Q/K region is dead once pT is computed; P writes below overwrite it.
    #pragma unroll
    for (int n4 = 0; n4 < 4; ++n4) {
        float a_[4][4]; float mx = -INFINITY;
        #pragma unroll
        for (int m4 = 0; m4 < 4; ++m4)
            #pragma unroll
            for (int r = 0; r < 4; ++r) {
                float mj = mjv[m4][r];
                float av = pT[m4][n4][r] * 0.25f * mj - (1.f - mj) * NEGBIG;
                a_[m4][r] = av; mx = fmaxf(mx, av);
            }
        mx = fmaxf(mx, __shfl_xor(mx, 16)); mx = fmaxf(mx, __shfl_xor(mx, 32));
        float sm = 0.f;
        #pragma unroll
        for (int m4 = 0; m4 < 4; ++m4)
            #pragma unroll
            for (int r = 0; r < 4; ++r) { float e = __expf(a_[m4][r] - mx); a_[m4][r] = e; sm += e; }
        sm += __shfl_xor(sm, 16); sm += __shfl_xor(sm, 32);
        float inv = rcpf(sm);
        int i = t + 16 * n4;
        if (i < SEQ) {
            #pragma unroll
            for (int m4 = 0; m4 < 4; ++m4) {
                f16x4 pk;
                #pragma unroll
                for (int r = 0; r < 4; ++r) pk[r] = (f16)(a_[m4][r] * inv);
                *(f16x4*)(wa + swzP(i, (16 * m4 + 4 * g) * 2)) = pk;   // P[i][j]
            }
        }
    }

    // ================= phase F: out = P @ v =================
    f16x8 bv[3][2];
    #pragma unroll
    for (int nt = 0; nt < 3; ++nt)
        #pragma unroll
        for (int kt = 0; kt < 2; ++kt)
            bv[nt][kt] = *(f16x8*)(wa + swzV(t + 16 * nt, (32 * kt + 8 * g) * 2));

    f32x4 oA[4][3];
    #pragma unroll
    for (int mt = 0; mt < 4; ++mt)
        #pragma unroll
        for (int nt = 0; nt < 3; ++nt) { f32x4 z; z[0]=0.f; z[1]=0.f; z[2]=0.f; z[3]=0.f; oA[mt][nt] = z; }

    #pragma unroll
    for (int mt = 0; mt < 4; ++mt) {
        int pr = 16 * mt + t; if (pr > SEQ - 1) pr = SEQ - 1;      // clamp: rows >=50 masked later
        #pragma unroll
        for (int kt = 0; kt < 2; ++kt) {
            f16x8 ap = *(f16x8*)(wa + swzP(pr, (32 * kt + 8 * g) * 2));
            #pragma unroll
            for (int nt = 0; nt < 3; ++nt)
                oA[mt][nt] = __builtin_amdgcn_mfma_f32_16x16x32_f16(ap, bv[nt][kt], oA[mt][nt], 0, 0, 0);
        }
    }

    // out -> out_lds (reuse P region): out[i = 4g+r+16mt][u = t+16nt], f16
    #pragma unroll
    for (int mt = 0; mt < 4; ++mt)
        #pragma unroll
        for (int nt = 0; nt < 3; ++nt) {
            int u = t + 16 * nt;
            if (u < UNITD) {
                #pragma unroll
                for (int r = 0; r < 4; ++r) {
                    int i = 4 * g + r + 16 * mt;
                    if (i < SEQ)
                        *(f16*)(wa + swzP(i, u * 2)) = (f16)oA[mt][nt][r];
                }
            }
        }

    // ================= phase G: out2^T = Wo @ out^T (+bo) =================
    f16x8 aw[3][2];
    #pragma unroll
    for (int mo = 0; mo < 3; ++mo)
        #pragma unroll
        for (int kt = 0; kt < 2; ++kt)
            aw[mo][kt] = wf[512 + (mo * 2 + kt) * 64 + lane];

    f32x4 o2[3][4];
    #pragma unroll
    for (int mo = 0; mo < 3; ++mo)
        #pragma unroll
        for (int n4 = 0; n4 < 4; ++n4) { f32x4 z; z[0]=0.f; z[1]=0.f; z[2]=0.f; z[3]=0.f; o2[mo][n4] = z; }

    #pragma unroll
    for (int n4 = 0; n4 < 4; ++n4) {
        int br = t + 16 * n4; if (br > SEQ - 1) br = SEQ - 1;      // clamp: cols >=50 masked later
        #pragma unroll
        for (int kt = 0; kt < 2; ++kt) {
            f16x8 bo_ = *(f16x8*)(wa + swzP(br, (32 * kt + 8 * g) * 2));
            #pragma unroll
            for (int mo = 0; mo < 3; ++mo)
                o2[mo][n4] = __builtin_amdgcn_mfma_f32_16x16x32_f16(aw[mo][kt], bo_, o2[mo][n4], 0, 0, 0);
        }
    }

    float bov[3][4], wqv[3][4];
    #pragma unroll
    for (int mo = 0; mo < 3; ++mo)
        #pragma unroll
        for (int r = 0; r < 4; ++r) {
            int o = 16 * mo + 4 * g + r; bool ok2 = (o < UNITD);
            bov[mo][r] = ok2 ? bo[o] : 0.f;
            wqv[mo][r] = ok2 ? Wq[o] : 0.f;
        }
    #pragma unroll
    for (int mo = 0; mo < 3; ++mo)
        #pragma unroll
        for (int n4 = 0; n4 < 4; ++n4)
            #pragma unroll
            for (int r = 0; r < 4; ++r) o2[mo][n4][r] += bov[mo][r];

    // ================= phase H: prob = softmax_i(out2 . Wq + bq, masked) =================
    float bq0 = bq[0];
    float tv[4]; float mx2 = -INFINITY;
    #pragma unroll
    for (int n4 = 0; n4 < 4; ++n4) {
        float s = 0.f;
        #pragma unroll
        for (int mo = 0; mo < 3; ++mo)
            #pragma unroll
            for (int r = 0; r < 4; ++r) s += o2[mo][n4][r] * wqv[mo][r];
        s += __shfl_xor(s, 16); s += __shfl_xor(s, 32);
        float hq = s + bq0;
        float mi = M[t + 16 * n4];
        tv[n4] = hq * mi - (1.f - mi) * NEGBIG;
        mx2 = fmaxf(mx2, tv[n4]);
    }
    #pragma unroll
    for (int off = 1; off <= 8; off <<= 1) mx2 = fmaxf(mx2, __shfl_xor(mx2, off));
    float sm2 = 0.f;
    #pragma unroll
    for (int n4 = 0; n4 < 4; ++n4) { float e = __expf(tv[n4] - mx2); tv[n4] = e; sm2 += e; }
    #pragma unroll
    for (int off = 1; off <= 8; off <<= 1) sm2 += __shfl_xor(sm2, off);
    float inv2 = rcpf(sm2);

    // ================= phase I: result[o] = sum_i out2[i][o] * prob[i] =================
    #pragma unroll
    for (int mo = 0; mo < 3; ++mo) {
        float racc[4];
        #pragma unroll
        for (int r = 0; r < 4; ++r) {
            float a = 0.f;
            #pragma unroll
            for (int n4 = 0; n4 < 4; ++n4) a += o2[mo][n4][r] * tv[n4];
            racc[r] = a;
        }
        #pragma unroll
        for (int off = 1; off <= 8; off <<= 1)
            #pragma unroll
            for (int r = 0; r < 4; ++r) racc[r] += __shfl_xor(racc[r], off);
        if (t == 0) {
            #pragma unroll
            for (int r = 0; r < 4; ++r) {
                int o = 16 * mo + 4 * g + r;
                if (o < UNITD) out[(size_t)b * UNITD + o] = racc[r] * inv2;
            }
        }
    }
}

extern "C" void kernel_launch(void* const* d_in, const int* in_sizes, int n_in,
                              void* d_out, int out_size, void* d_ws, size_t ws_size,
                              hipStream_t stream) {
    const float* x    = (const float*)d_in[0];
    const float* mask = (const float*)d_in[1];
    const float* Wi   = (const float*)d_in[2];
    const float* bi   = (const float*)d_in[3];
    const float* Wo   = (const float*)d_in[4];
    const float* bo   = (const float*)d_in[5];
    const float* sq   = (const float*)d_in[6];
    const float* oq   = (const float*)d_in[7];
    const float* sk   = (const float*)d_in[8];
    const float* ok   = (const float*)d_in[9];
    const float* Wq   = (const float*)d_in[10];
    const float* bq   = (const float*)d_in[11];
    float* outp       = (float*)d_out;

    prep_kernel<<<1, 64, 0, stream>>>(Wi, Wo, (f16x8*)d_ws);

    const int B = in_sizes[0] / (SEQ * UNITD);
    const int blocks = (B + 3) / 4;
    gau_kernel<<<blocks, 256, 0, stream>>>(x, mask, (const f16x8*)d_ws, bi, bo,
                                           sq, oq, sk, ok, Wq, bq, outp, B);
}